// Round 1
// 6548.971 us; speedup vs baseline: 1.0248x; 1.0248x over previous
//
#include <hip/hip_runtime.h>
#include <stdint.h>

typedef unsigned short u16;
using bf16x8 = __attribute__((ext_vector_type(8))) short;
using f32x4  = __attribute__((ext_vector_type(4))) float;

__device__ __forceinline__ float b2f(u16 v) {
  return __uint_as_float(((uint32_t)v) << 16);
}
__device__ __forceinline__ u16 f2b(float f) {
  uint32_t u = __float_as_uint(f);
  u = u + 0x7fffu + ((u >> 16) & 1u);
  return (u16)(u >> 16);
}
__device__ __forceinline__ float ldf(const void* p, size_t i, int f32) {
  return f32 ? ((const float*)p)[i] : b2f(((const u16*)p)[i]);
}
__device__ __forceinline__ float sigf(float x) {
  return __builtin_amdgcn_rcpf(1.f + __expf(-x));
}
__device__ __forceinline__ float tanhf_fast(float x) {
  x = fminf(fmaxf(x, -15.f), 15.f);
  float e = __expf(2.f * x);
  return (e - 1.f) * __builtin_amdgcn_rcpf(e + 1.f);
}

// ---------------------------------------------------------------------------
// Dtype detector: sample first 1024 u16s of x_enc (values ~N(0,1)).
// ---------------------------------------------------------------------------
__global__ __launch_bounds__(1024) void k_detect(const u16* __restrict__ x, int* flag) {
  int tid = threadIdx.x;
  u16 v = x[tid];
  int e = (v >> 7) & 0xFF;
  int ok = (e >= 100 && e <= 140) ? 1 : 0;
#pragma unroll
  for (int o = 32; o > 0; o >>= 1) ok += __shfl_down(ok, o);
  __shared__ int s[16];
  if ((tid & 63) == 0) s[tid >> 6] = ok;
  __syncthreads();
  if (tid == 0) {
    int c = 0;
#pragma unroll
    for (int i = 0; i < 16; ++i) c += s[i];
    *flag = (c < 900) ? 1 : 0;
  }
}

__global__ __launch_bounds__(256) void k_conv(u16* __restrict__ dst, const void* __restrict__ src,
                                              int n, const int* __restrict__ flagp) {
  int f32 = *flagp;
  int i = blockIdx.x * 256 + threadIdx.x;
  if (i < n) dst[i] = f32 ? f2b(((const float*)src)[i]) : ((const u16*)src)[i];
}

__global__ __launch_bounds__(256) void k_bias(float* __restrict__ bias, const void* b_ih,
                                              const void* b_hh, const int* __restrict__ flagp) {
  int f32 = *flagp;
  int n = blockIdx.x * 256 + threadIdx.x;
  if (n < 2048) bias[n] = ldf(b_ih, n, f32) + ldf(b_hh, n, f32);
}

// ---------------------------------------------------------------------------
// Generic NT GEMM: C[m,n] = sum_k A[m,k]*B[n,k].  (unchanged from prior round)
// ---------------------------------------------------------------------------
template<int EPI>
__global__ __launch_bounds__(256) void gemm_bt(
    const u16* __restrict__ A, int lda,
    const void* __restrict__ B, int ldb,
    int M, int K,
    void* __restrict__ C,
    const float* __restrict__ bias,
    int ldc, const int* __restrict__ flagp)
{
  __shared__ __align__(16) u16 As[128 * 32];
  __shared__ __align__(16) u16 Bs[128 * 32];
  const int f32  = *flagp;
  const int tid  = threadIdx.x;
  const int lane = tid & 63;
  const int wv   = tid >> 6;
  const int wm   = (wv >> 1) * 64;
  const int wn   = (wv & 1) * 64;
  const int n0   = blockIdx.x * 128;
  const int m0   = blockIdx.y * 128;
  const int lr   = lane & 15;
  const int lk   = (lane >> 4) * 8;

  f32x4 acc[4][4] = {};

  for (int k0 = 0; k0 < K; k0 += 32) {
    __syncthreads();
#pragma unroll
    for (int c = 0; c < 2; ++c) {
      int idx = tid + c * 256;
      int row = idx >> 2;
      int col = (idx & 3) * 8;
      int ar = m0 + row; if (ar > M - 1) ar = M - 1;
      *(uint4*)&As[idx * 8] = *(const uint4*)&A[(size_t)ar * lda + k0 + col];
      int br = n0 + row;
      if (f32) {
        const float* bp = (const float*)B + (size_t)br * ldb + k0 + col;
        float4 x0 = *(const float4*)bp;
        float4 x1 = *(const float4*)(bp + 4);
        uint4 pk;
        pk.x = (uint32_t)f2b(x0.x) | ((uint32_t)f2b(x0.y) << 16);
        pk.y = (uint32_t)f2b(x0.z) | ((uint32_t)f2b(x0.w) << 16);
        pk.z = (uint32_t)f2b(x1.x) | ((uint32_t)f2b(x1.y) << 16);
        pk.w = (uint32_t)f2b(x1.z) | ((uint32_t)f2b(x1.w) << 16);
        *(uint4*)&Bs[idx * 8] = pk;
      } else {
        *(uint4*)&Bs[idx * 8] = *(const uint4*)((const u16*)B + (size_t)br * ldb + k0 + col);
      }
    }
    __syncthreads();
    bf16x8 af[4], bfr[4];
#pragma unroll
    for (int i = 0; i < 4; ++i) {
      af[i]  = *(const bf16x8*)&As[(wm + i * 16 + lr) * 32 + lk];
      bfr[i] = *(const bf16x8*)&Bs[(wn + i * 16 + lr) * 32 + lk];
    }
#pragma unroll
    for (int i = 0; i < 4; ++i)
#pragma unroll
      for (int j = 0; j < 4; ++j)
        acc[i][j] = __builtin_amdgcn_mfma_f32_16x16x32_bf16(af[i], bfr[j], acc[i][j], 0, 0, 0);
  }

#pragma unroll
  for (int i = 0; i < 4; ++i) {
#pragma unroll
    for (int j = 0; j < 4; ++j) {
#pragma unroll
      for (int r = 0; r < 4; ++r) {
        int m = m0 + wm + i * 16 + (lane >> 4) * 4 + r;
        int n = n0 + wn + j * 16 + lr;
        if (m < M) {
          float v = acc[i][j][r];
          if (EPI == 0) {
            ((u16*)C)[(size_t)m * ldc + n] = f2b(v + bias[n]);
          } else if (EPI == 1) {
            ((u16*)C)[(size_t)m * ldc + n] = f2b(tanhf_fast(v));
          } else {
            int tt = m >> 5, bb = m & 31;
            size_t off = (size_t)bb * 4064000 + (size_t)tt * 32000 + n;
            if (f32) ((float*)C)[off] = v;
            else     ((u16*)C)[off] = f2b(v);
          }
        }
      }
    }
  }
}

// ---------------------------------------------------------------------------
// Device-scope ticket grid barrier (128 blocks, all co-resident: 1 block/CU).
// cnt is monotonically increasing; zeroed by k_init each launch.
// ---------------------------------------------------------------------------
#define NBLK 128
__device__ __forceinline__ void gbar(int* cnt) {
  __syncthreads();
  if (threadIdx.x == 0) {
    __threadfence();
    int t = __hip_atomic_fetch_add(cnt, 1, __ATOMIC_ACQ_REL, __HIP_MEMORY_SCOPE_AGENT);
    int target = (t / NBLK + 1) * NBLK;
    while (__hip_atomic_load(cnt, __ATOMIC_ACQUIRE, __HIP_MEMORY_SCOPE_AGENT) < target) {
      __builtin_amdgcn_s_sleep(1);
    }
    __threadfence();
  }
  __syncthreads();
}

// ---------------------------------------------------------------------------
// Persistent kernel: all 127 recurrent steps in one launch.
// 128 blocks x 256 threads. Block j owns:
//   - gate columns j*4..j*4+3 (16 W3 rows in LDS, c_state in LDS)
//   - q dims j*4..j*4+3 (W_trg slice + x_enc_k slice in LDS) -> partial scores
//   - ctx quarter (b=j>>2, dq=j&3) with swizzled x_enc slice in LDS
// Per step: A(gates+cell+h) | bar | B(q+partial scores) | bar | C(softmax+ctx) | bar
// ---------------------------------------------------------------------------
__global__ __launch_bounds__(256, 1) void k_loop(
    const u16* __restrict__ W3,         // [2048][1536]
    const u16* __restrict__ pregates,   // [4064][2048]
    const u16* __restrict__ cxek,       // [32][64][512]
    const u16* __restrict__ cxe,        // [32][64][1024]
    const u16* __restrict__ cW_trg,     // [512][512]
    const u16* __restrict__ cb_trg,     // [512]
    const u16* __restrict__ cW_att,     // [512]
    const float* __restrict__ c_state,  // [32][512]
    u16* __restrict__ inpA,             // [32][1536] ping
    u16* __restrict__ inpB,             // [32][1536] pong
    u16* __restrict__ hctx,             // [127][32][1536]
    float* __restrict__ ps,             // [32][128][64] partial scores
    int* __restrict__ bar)
{
  const int j   = blockIdx.x;
  const int tid = threadIdx.x;

  __shared__ __align__(16) u16 w3s[16][1544];   // 16 gate rows, padded (+8) vs 32-bank conflicts
  __shared__ __align__(16) u16 wtg[4][520];     // W_trg rows j*4..+3, padded
  __shared__ __align__(16) u16 xek[32 * 64 * 4];// x_enc_k[b][l][j*4..+3]
  __shared__ __align__(16) u16 xes[256 * 64];   // x_enc[b=j>>2][l][dq*256+d], [d][l] XOR-swizzled
  __shared__ __align__(16) u16 hs[32][520];     // staged h, padded
  __shared__ float gsum[4][32][17];             // per-wave partial gates (pad 17)
  __shared__ float qs[128];                     // q[b][r] for this block's 4 dims
  __shared__ float scp[4][64];
  __shared__ float wts[64];
  __shared__ float wa4[4], btg4[4];
  __shared__ float cls[128];                    // c_state for this block's 4 cols

  // ---- one-time init: load LDS-resident state ----
  for (int i = tid; i < 16 * 192; i += 256) {
    int row = i / 192, cc = (i % 192) * 8;
    int gr = (row >> 2) * 512 + j * 4 + (row & 3);
    *(uint4*)&w3s[row][cc] = *(const uint4*)&W3[(size_t)gr * 1536 + cc];
  }
  for (int i = tid; i < 4 * 64; i += 256) {
    int r = i >> 6, cc = (i & 63) * 8;
    *(uint4*)&wtg[r][cc] = *(const uint4*)&cW_trg[((size_t)(j * 4 + r)) * 512 + cc];
  }
  for (int i = tid; i < 2048; i += 256) {       // (b,l) -> 4 halves
    int b = i >> 6, l = i & 63;
    *(uint2*)&xek[i * 4] = *(const uint2*)&cxek[((size_t)b * 64 + l) * 512 + j * 4];
  }
  for (int i = tid; i < 2048; i += 256) {       // (d, l-chunk c), transposed + swizzled
    int d = i >> 3, c = i & 7;
    bf16x8 v;
#pragma unroll
    for (int e = 0; e < 8; ++e)
      v[e] = (short)cxe[((size_t)(j >> 2) * 64 + c * 8 + e) * 1024 + (j & 3) * 256 + d];
    *(bf16x8*)&xes[d * 64 + ((c ^ (d & 7)) * 8)] = v;
  }
  if (tid < 4) { wa4[tid] = b2f(cW_att[j * 4 + tid]); btg4[tid] = b2f(cb_trg[j * 4 + tid]); }
  if (tid < 128) cls[tid] = c_state[(tid >> 2) * 512 + j * 4 + (tid & 3)];
  __syncthreads();

  u16* inp  = inpA;
  u16* inpn = inpB;

  for (int t = 0; t < 127; ++t) {
    // ================= Phase A: gates GEMM + LSTM cell =================
    {
      const int lane = tid & 63, wv = tid >> 6;
      const int lr = lane & 15, lk = (lane >> 4) * 8;
      f32x4 acc0 = {}, acc1 = {};
      const u16* Ar0 = inp + lr * 1536 + wv * 384 + lk;
      const u16* Ar1 = Ar0 + 16 * 1536;
      const u16* Br  = &w3s[lr][wv * 384 + lk];
#pragma unroll 6
      for (int it = 0; it < 12; ++it) {
        bf16x8 a0 = *(const bf16x8*)(Ar0 + it * 32);
        bf16x8 a1 = *(const bf16x8*)(Ar1 + it * 32);
        bf16x8 bb = *(const bf16x8*)(Br + it * 32);
        acc0 = __builtin_amdgcn_mfma_f32_16x16x32_bf16(a0, bb, acc0, 0, 0, 0);
        acc1 = __builtin_amdgcn_mfma_f32_16x16x32_bf16(a1, bb, acc1, 0, 0, 0);
      }
#pragma unroll
      for (int r = 0; r < 4; ++r) {
        int m = (lane >> 4) * 4 + r;
        gsum[wv][m][lr]      = acc0[r];
        gsum[wv][m + 16][lr] = acc1[r];
      }
    }
    __syncthreads();
    if (tid < 128) {
      const int b = tid >> 2, r = tid & 3;
      float gv[4];
#pragma unroll
      for (int g = 0; g < 4; ++g) {
        int n = g * 4 + r;
        float s = gsum[0][b][n] + gsum[1][b][n] + gsum[2][b][n] + gsum[3][b][n];
        gv[g] = s + b2f(pregates[((size_t)t * 32 + b) * 2048 + g * 512 + j * 4 + r]);
      }
      float cn = sigf(gv[1]) * cls[tid] + sigf(gv[0]) * tanhf_fast(gv[2]);
      float hh = sigf(gv[3]) * tanhf_fast(cn);
      cls[tid] = cn;
      u16 hb = f2b(hh);
      int col = j * 4 + r;
      inpn[b * 1536 + 1024 + col] = hb;
      hctx[((size_t)t * 32 + b) * 1536 + col] = hb;
    }
    gbar(bar);

    // ================= Phase B: q (4 dims) + partial scores =================
    for (int i = tid; i < 32 * 64; i += 256) {
      int b = i >> 6, cc = (i & 63) * 8;
      *(uint4*)&hs[b][cc] = *(const uint4*)&inpn[b * 1536 + 1024 + cc];
    }
    __syncthreads();
    {
      const int o = tid >> 1, kh = tid & 1;
      const int b = o >> 2, r = o & 3;
      float acc = 0.f;
      const u16* hr = &hs[b][kh * 256];
      const u16* wr = &wtg[r][kh * 256];
#pragma unroll 8
      for (int k = 0; k < 256; k += 8) {
        bf16x8 hv  = *(const bf16x8*)(hr + k);
        bf16x8 wv8 = *(const bf16x8*)(wr + k);
#pragma unroll
        for (int e = 0; e < 8; ++e) acc += b2f((u16)hv[e]) * b2f((u16)wv8[e]);
      }
      acc += __shfl_xor(acc, 1);
      if (kh == 0) qs[o] = acc + btg4[r];
    }
    __syncthreads();
    {
      const int b = tid >> 3, lg = tid & 7;
      const float q0 = qs[b * 4 + 0], q1 = qs[b * 4 + 1];
      const float q2 = qs[b * 4 + 2], q3 = qs[b * 4 + 3];
      const float w0 = wa4[0], w1 = wa4[1], w2 = wa4[2], w3v = wa4[3];
      float* pdst = ps + ((size_t)b * 128 + j) * 64 + lg * 8;
#pragma unroll
      for (int il = 0; il < 8; ++il) {
        int l = lg * 8 + il;
        const u16* xk = &xek[(b * 64 + l) * 4];
        float s = w0 * tanhf_fast(b2f(xk[0]) + q0) + w1 * tanhf_fast(b2f(xk[1]) + q1)
                + w2 * tanhf_fast(b2f(xk[2]) + q2) + w3v * tanhf_fast(b2f(xk[3]) + q3);
        pdst[il] = s;
      }
    }
    gbar(bar);

    // ================= Phase C: softmax + ctx quarter =================
    {
      const int cb = j >> 2, dq = j & 3;
      {
        const int l = tid & 63, part = tid >> 6;
        const float* pp = ps + ((size_t)cb * 128 + part * 32) * 64 + l;
        float s = 0.f;
#pragma unroll 8
        for (int jj = 0; jj < 32; ++jj) s += pp[jj * 64];
        scp[part][l] = s;
      }
      __syncthreads();
      if (tid < 64) {
        float s = scp[0][tid] + scp[1][tid] + scp[2][tid] + scp[3][tid];
        float mx = s;
#pragma unroll
        for (int o = 32; o > 0; o >>= 1) mx = fmaxf(mx, __shfl_xor(mx, o));
        float e = __expf(s - mx);
        float sm = e;
#pragma unroll
        for (int o = 32; o > 0; o >>= 1) sm += __shfl_xor(sm, o);
        wts[tid] = e * __builtin_amdgcn_rcpf(sm);
      }
      __syncthreads();
      {
        float acc = 0.f;
        const int dsw = tid & 7;
#pragma unroll
        for (int c = 0; c < 8; ++c) {
          bf16x8 v = *(const bf16x8*)&xes[tid * 64 + ((c ^ dsw) * 8)];
#pragma unroll
          for (int e = 0; e < 8; ++e) acc += wts[c * 8 + e] * b2f((u16)v[e]);
        }
        u16 cv = f2b(acc);
        int col = dq * 256 + tid;
        inpn[cb * 1536 + col] = cv;
        hctx[((size_t)t * 32 + cb) * 1536 + 512 + col] = cv;
      }
    }
    gbar(bar);

    u16* tmp = inp; inp = inpn; inpn = tmp;
  }
}

// ---------------------------------------------------------------------------
// Setup kernels (dtype-aware)
// ---------------------------------------------------------------------------
__global__ __launch_bounds__(256) void k_gather(
    const int* __restrict__ x_train, const int* __restrict__ y_train,
    const void* __restrict__ word_emb, const void* __restrict__ attr_tab,
    u16* __restrict__ A_x, const int* __restrict__ flagp)
{
  int f32 = *flagp;
  int idx = blockIdx.x * 256 + threadIdx.x;
  if (idx >= 4064 * 1024) return;
  int m = idx >> 10, k = idx & 1023;
  int t = m >> 5, b = m & 31;
  u16 v;
  if (k < 512) {
    v = f2b(ldf(word_emb, (size_t)x_train[b * 128 + t] * 512 + k, f32));
  } else {
    int d = k - 512;
    float a = ldf(attr_tab, (size_t)y_train[b * 2] * 512 + d, f32) +
              ldf(attr_tab, (size_t)y_train[b * 2 + 1] * 512 + d, f32);
    v = f2b(a);
  }
  A_x[idx] = v;
}

__global__ __launch_bounds__(256) void k_w3(
    const void* __restrict__ W_ih, const void* __restrict__ W_hh,
    u16* __restrict__ W3, const int* __restrict__ flagp)
{
  int f32 = *flagp;
  int idx = blockIdx.x * 256 + threadIdx.x;
  if (idx >= 2048 * 1536) return;
  int n = idx / 1536, k = idx - n * 1536;
  float v = (k < 1024) ? ldf(W_ih, (size_t)n * 2048 + 1024 + k, f32)
                       : ldf(W_hh, (size_t)n * 512 + (k - 1024), f32);
  W3[idx] = f2b(v);
}

__global__ __launch_bounds__(256) void k_init(
    const void* __restrict__ dec_h0, const void* __restrict__ dec_c0,
    u16* __restrict__ inpA, float* __restrict__ c_state,
    int* __restrict__ bar, const int* __restrict__ flagp)
{
  int f32 = *flagp;
  int idx = blockIdx.x * 256 + threadIdx.x;
  if (idx < 32 * 1536) {
    int m = idx / 1536, c = idx - m * 1536;
    inpA[idx] = (c < 1024) ? (u16)0 : f2b(ldf(dec_h0, m * 512 + (c - 1024), f32));
  }
  if (idx < 32 * 512) c_state[idx] = ldf(dec_c0, idx, f32);
  if (idx < 8) bar[idx] = 0;
}

// ---------------------------------------------------------------------------
extern "C" void kernel_launch(void* const* d_in, const int* in_sizes, int n_in,
                              void* d_out, int out_size, void* d_ws, size_t ws_size,
                              hipStream_t stream)
{
  const void* x_enc    = d_in[0];
  const void* x_enc_k  = d_in[1];
  const void* dec_h0   = d_in[2];
  const void* dec_c0   = d_in[3];
  const int* y_train   = (const int*)d_in[5];
  const int* x_train   = (const int*)d_in[6];
  const void* word_emb = d_in[7];
  const void* attr_tab = d_in[8];
  const void* W_ih     = d_in[9];
  const void* W_hh     = d_in[10];
  const void* b_ih     = d_in[11];
  const void* b_hh     = d_in[12];
  const void* W_trg    = d_in[13];
  const void* b_trg    = d_in[14];
  const void* W_att    = d_in[15];
  const void* b_att    = d_in[16];
  const void* W_cr     = d_in[17];
  const void* W_ro     = d_in[18];
  (void)b_att; // softmax is shift-invariant; b_att cancels

  char* ws = (char*)d_ws;
  size_t off = 0;
  auto alloc = [&](size_t bytes) -> void* {
    void* p = ws + off;
    off += (bytes + 255) & ~(size_t)255;
    return p;
  };
  u16*   A_x      = (u16*)  alloc(4064ull * 1024 * 2);
  u16*   pregates = (u16*)  alloc(4064ull * 2048 * 2);
  u16*   W3       = (u16*)  alloc(2048ull * 1536 * 2);
  u16*   hctx     = (u16*)  alloc(4064ull * 1536 * 2);
  u16*   pre_all  = (u16*)  alloc(4064ull * 512 * 2);
  u16*   cxe      = (u16*)  alloc(32ull * 64 * 1024 * 2);
  u16*   cxek     = (u16*)  alloc(32ull * 64 * 512 * 2);
  u16*   cW_trg   = (u16*)  alloc(512ull * 512 * 2);
  u16*   cb_trg   = (u16*)  alloc(512 * 2);
  u16*   cW_att   = (u16*)  alloc(512 * 2);
  float* bias     = (float*)alloc(2048 * 4);
  u16*   inpA     = (u16*)  alloc(32 * 1536 * 2);
  u16*   inpB     = (u16*)  alloc(32 * 1536 * 2);
  float* c_state  = (float*)alloc(32 * 512 * 4);
  float* ps_buf   = (float*)alloc(32ull * 128 * 64 * 4);
  int*   bar      = (int*)  alloc(256);
  int*   flag     = (int*)  alloc(256);

  k_detect<<<1, 1024, 0, stream>>>((const u16*)x_enc, flag);

  k_conv<<<(2097152 + 255) / 256, 256, 0, stream>>>(cxe, x_enc, 2097152, flag);
  k_conv<<<(1048576 + 255) / 256, 256, 0, stream>>>(cxek, x_enc_k, 1048576, flag);
  k_conv<<<(262144 + 255) / 256, 256, 0, stream>>>(cW_trg, W_trg, 262144, flag);
  k_conv<<<2, 256, 0, stream>>>(cb_trg, b_trg, 512, flag);
  k_conv<<<2, 256, 0, stream>>>(cW_att, W_att, 512, flag);
  k_bias<<<8, 256, 0, stream>>>(bias, b_ih, b_hh, flag);

  k_init<<<192, 256, 0, stream>>>(dec_h0, dec_c0, inpA, c_state, bar, flag);
  k_gather<<<(4064 * 1024 + 255) / 256, 256, 0, stream>>>(x_train, y_train, word_emb, attr_tab, A_x, flag);
  k_w3<<<(2048 * 1536 + 255) / 256, 256, 0, stream>>>(W_ih, W_hh, W3, flag);

  // pre_gates = [x_emb|attr] @ W_ih[:, :1024].T + (b_ih + b_hh)
  gemm_bt<0><<<dim3(16, 32), 256, 0, stream>>>(
      A_x, 1024, W_ih, 2048, 4064, 1024, pregates, bias, 2048, flag);

  // all 127 recurrent steps in one persistent launch
  k_loop<<<NBLK, 256, 0, stream>>>(W3, pregates, cxek, cxe, cW_trg, cb_trg, cW_att,
                                   c_state, inpA, inpB, hctx, ps_buf, bar);

  // pre = tanh([h|ctx] @ W_cr.T)
  gemm_bt<1><<<dim3(4, 32), 256, 0, stream>>>(
      hctx, 1536, W_cr, 1536, 4064, 1536, pre_all, nullptr, 512, flag);
  // logits = pre @ W_ro.T  -> out[b][t][v]
  gemm_bt<2><<<dim3(250, 32), 256, 0, stream>>>(
      pre_all, 512, W_ro, 512, 4064, 512, d_out, nullptr, 32000, flag);
}